// Round 1
// baseline (2542.319 us; speedup 1.0000x reference)
//
#include <hip/hip_runtime.h>
#include <math.h>
#include <stdio.h>

#define NROWS 8192
#define KDIM 2048
#define VOCAB 50257
#define VOCAB_PAD 50304   // 393 * 128
#define NTILES 393
#define NCHUNKS 32
#define BM 128
#define BN 128
#define BK 64
#define KSTEPS (KDIM / BK)   // 32
#define ROWBLKS (NROWS / BM) // 64
#define L2E 1.44269504088896340736f

typedef __bf16 bf16x8 __attribute__((ext_vector_type(8)));
typedef float f32x4 __attribute__((ext_vector_type(4)));

__device__ __forceinline__ unsigned short f2b(float f) {
  unsigned int u = __float_as_uint(f);
  u += 0x7fffu + ((u >> 16) & 1u);   // round-to-nearest-even
  return (unsigned short)(u >> 16);
}

// async global->LDS, 16B per lane, wave-uniform LDS base + lane*16
#define GLL16(g, l)                                                         \
  __builtin_amdgcn_global_load_lds(                                         \
      (const __attribute__((address_space(1))) void*)(g),                   \
      (__attribute__((address_space(3))) void*)(l), 16, 0, 0)

// ---------------- convert kernels (f32 -> bf16) ----------------
__global__ void convert_x_kernel(const float4* __restrict__ src,
                                 ushort4* __restrict__ dst) {
  const long long total = (long long)NROWS * KDIM / 4;
  for (long long i = (long long)blockIdx.x * blockDim.x + threadIdx.x;
       i < total; i += (long long)gridDim.x * blockDim.x) {
    float4 v = src[i];
    ushort4 o;
    o.x = f2b(v.x); o.y = f2b(v.y); o.z = f2b(v.z); o.w = f2b(v.w);
    dst[i] = o;
  }
}

__global__ void convert_w_kernel(const float4* __restrict__ src,
                                 ushort4* __restrict__ dst) {
  const long long total  = (long long)VOCAB_PAD * KDIM / 4;
  const long long stotal = (long long)VOCAB * KDIM / 4;
  for (long long i = (long long)blockIdx.x * blockDim.x + threadIdx.x;
       i < total; i += (long long)gridDim.x * blockDim.x) {
    float4 v;
    if (i < stotal) v = src[i];
    else { v.x = v.y = v.z = v.w = 0.f; }  // zero pad rows
    ushort4 o;
    o.x = f2b(v.x); o.y = f2b(v.y); o.z = f2b(v.z); o.w = f2b(v.w);
    dst[i] = o;
  }
}

// ---------------- fused GEMM + online softmax partials ----------------
// grid: 2048 blocks = 64 row-blocks x 32 vocab-chunks, 256 threads (4 waves, 2x2)
__global__ void __launch_bounds__(256, 2)
gemm_ce_kernel(const unsigned short* __restrict__ xb,
               const unsigned short* __restrict__ wb,
               const float* __restrict__ bias,
               const int* __restrict__ targ,
               float* __restrict__ pm, float* __restrict__ ps,
               float* __restrict__ tlogit) {
  __shared__ __align__(16) unsigned short Asm[BM][BK];  // 16 KB
  __shared__ __align__(16) unsigned short Bsm[BN][BK];  // 16 KB
  __shared__ float m_w[2][BM], s_w[2][BM];
  __shared__ float M_run[BM], S_run[BM];
  __shared__ int targ_s[BM];

  const int tid  = threadIdx.x;
  const int lane = tid & 63;
  const int w    = tid >> 6;       // wave 0..3
  const int wm   = w >> 1;         // wave row  (0,1) -> rows wm*64..
  const int wn   = w & 1;          // wave col  (0,1) -> cols wn*64..
  const int g    = lane >> 4;      // k-group / row-group
  const int c0   = lane & 15;

  const int bid    = blockIdx.x;
  const int rowblk = bid & 63;
  const int chunk  = bid >> 6;
  const int row0   = rowblk * BM;
  const int tile_start = (chunk * NTILES) / NCHUNKS;
  const int tile_end   = ((chunk + 1) * NTILES) / NCHUNKS;

  if (tid < BM) {
    int t = targ[row0 + tid];
    targ_s[tid] = (t < 0) ? 0 : t;
    M_run[tid] = -1e30f;
    S_run[tid] = 0.f;
  }
  __syncthreads();

  for (int tile = tile_start; tile < tile_end; ++tile) {
    const int vcol0 = tile * BN;

    f32x4 acc[4][4];
#pragma unroll
    for (int mf = 0; mf < 4; ++mf)
#pragma unroll
      for (int nf = 0; nf < 4; ++nf)
        acc[mf][nf] = (f32x4){0.f, 0.f, 0.f, 0.f};

    for (int kt = 0; kt < KSTEPS; ++kt) {
      const int kbase = kt * BK;
      // ---- stage A and B tiles: 16KB each, 16B/lane, 4 insts/wave/operand
#pragma unroll
      for (int it = 0; it < 4; ++it) {
        const int cbase = (it * 4 + w) * 64;       // wave-uniform chunk base
        const int cidx  = cbase + lane;            // 16B chunk index 0..1023
        const int r  = cidx >> 3;                  // tile row
        const int k8 = cidx & 7;                   // which 8-elem group in BK
        const unsigned short* gA =
            xb + (size_t)(row0 + r) * KDIM + kbase + k8 * 8;
        GLL16(const_cast<unsigned short*>(gA),
              (char*)&Asm[0][0] + cbase * 16);
        const unsigned short* gB =
            wb + (size_t)(vcol0 + r) * KDIM + kbase + k8 * 8;
        GLL16(const_cast<unsigned short*>(gB),
              (char*)&Bsm[0][0] + cbase * 16);
      }
      __syncthreads();   // drains global_load_lds (vmcnt0) + LDS visible

      // ---- compute: 2 k-substeps of 32, 16 MFMA each
#pragma unroll
      for (int ks = 0; ks < 2; ++ks) {
        bf16x8 af[4], bfr[4];
#pragma unroll
        for (int mf = 0; mf < 4; ++mf)
          af[mf] = *(const bf16x8*)&Asm[wm * 64 + mf * 16 + c0][ks * 32 + g * 8];
#pragma unroll
        for (int nf = 0; nf < 4; ++nf)
          bfr[nf] = *(const bf16x8*)&Bsm[wn * 64 + nf * 16 + c0][ks * 32 + g * 8];
#pragma unroll
        for (int mf = 0; mf < 4; ++mf)
#pragma unroll
          for (int nf = 0; nf < 4; ++nf)
            acc[mf][nf] = __builtin_amdgcn_mfma_f32_16x16x32_bf16(
                af[mf], bfr[nf], acc[mf][nf], 0, 0, 0);
      }
      __syncthreads();   // compute done before next stage overwrites
    }

    // ---- epilogue: bias add, mask, per-row max/sumexp, target capture
    float bv[4];
    int colv[4];
#pragma unroll
    for (int nf = 0; nf < 4; ++nf) {
      const int col = vcol0 + wn * 64 + nf * 16 + c0;
      colv[nf] = col;
      bv[nf] = (col < VOCAB) ? bias[col] : 0.f;
    }
#pragma unroll
    for (int mf = 0; mf < 4; ++mf) {
#pragma unroll
      for (int reg = 0; reg < 4; ++reg) {
        const int rl = wm * 64 + mf * 16 + g * 4 + reg;  // local row
        const int t  = targ_s[rl];
        float vals[4];
        float vmax = -1e30f;
#pragma unroll
        for (int nf = 0; nf < 4; ++nf) {
          float v = acc[mf][nf][reg] + bv[nf];
          v = (colv[nf] < VOCAB) ? v : -1e30f;
          vals[nf] = v;
          vmax = fmaxf(vmax, v);
          if (colv[nf] == t) tlogit[row0 + rl] = v;  // exactly one lane matches
        }
        // reduce across the 16 lanes (c0) holding this row
        vmax = fmaxf(vmax, __shfl_xor(vmax, 1));
        vmax = fmaxf(vmax, __shfl_xor(vmax, 2));
        vmax = fmaxf(vmax, __shfl_xor(vmax, 4));
        vmax = fmaxf(vmax, __shfl_xor(vmax, 8));
        float ss = 0.f;
#pragma unroll
        for (int nf = 0; nf < 4; ++nf)
          ss += exp2f((vals[nf] - vmax) * L2E);
        ss += __shfl_xor(ss, 1);
        ss += __shfl_xor(ss, 2);
        ss += __shfl_xor(ss, 4);
        ss += __shfl_xor(ss, 8);
        if (c0 == 0) { m_w[wn][rl] = vmax; s_w[wn][rl] = ss; }
      }
    }
    __syncthreads();
    if (tid < BM) {   // combine the two col-waves, then online-merge
      const float m0 = m_w[0][tid], m1 = m_w[1][tid];
      const float s0 = s_w[0][tid], s1 = s_w[1][tid];
      const float mt = fmaxf(m0, m1);
      const float st = s0 * exp2f((m0 - mt) * L2E) + s1 * exp2f((m1 - mt) * L2E);
      const float M = M_run[tid], S = S_run[tid];
      const float nm = fmaxf(M, mt);
      S_run[tid] = S * exp2f((M - nm) * L2E) + st * exp2f((mt - nm) * L2E);
      M_run[tid] = nm;
    }
    __syncthreads();
  }

  if (tid < BM) {
    pm[(size_t)chunk * NROWS + row0 + tid] = M_run[tid];
    ps[(size_t)chunk * NROWS + row0 + tid] = S_run[tid];
  }
}

// ---------------- merge partials -> per-row NLL ----------------
__global__ void merge_rows_kernel(const float* __restrict__ pm,
                                  const float* __restrict__ ps,
                                  const float* __restrict__ tlogit,
                                  const int* __restrict__ targ,
                                  float* __restrict__ nll) {
  const int r = blockIdx.x * blockDim.x + threadIdx.x;
  if (r >= NROWS) return;
  float M = -1e30f;
#pragma unroll 4
  for (int j = 0; j < NCHUNKS; ++j) M = fmaxf(M, pm[j * NROWS + r]);
  float S = 0.f;
#pragma unroll 4
  for (int j = 0; j < NCHUNKS; ++j)
    S += ps[j * NROWS + r] * exp2f((pm[j * NROWS + r] - M) * L2E);
  const int t = targ[r];
  nll[r] = (t == -100) ? 0.f : (M + logf(S) - tlogit[r]);
}

// ---------------- final mean ----------------
__global__ void final_reduce_kernel(const float* __restrict__ nll,
                                    const int* __restrict__ targ,
                                    float* __restrict__ out) {
  __shared__ float ssum[256];
  __shared__ float scnt[256];
  const int tid = threadIdx.x;
  float s = 0.f, c = 0.f;
  for (int r = tid; r < NROWS; r += 256) {
    s += nll[r];
    c += (targ[r] != -100) ? 1.f : 0.f;
  }
  ssum[tid] = s; scnt[tid] = c;
  __syncthreads();
  for (int off = 128; off > 0; off >>= 1) {
    if (tid < off) { ssum[tid] += ssum[tid + off]; scnt[tid] += scnt[tid + off]; }
    __syncthreads();
  }
  if (tid == 0) out[0] = ssum[0] / fmaxf(scnt[0], 1.f);
}

extern "C" void kernel_launch(void* const* d_in, const int* in_sizes, int n_in,
                              void* d_out, int out_size, void* d_ws, size_t ws_size,
                              hipStream_t stream) {
  const float* x    = (const float*)d_in[0];
  const float* W    = (const float*)d_in[1];
  const float* bias = (const float*)d_in[2];
  const int*   targ = (const int*)d_in[3];
  float* out = (float*)d_out;

  char* ws = (char*)d_ws;
  const size_t wb_bytes  = (size_t)VOCAB_PAD * KDIM * 2;  // 206,045,184
  const size_t xb_bytes  = (size_t)NROWS * KDIM * 2;      //  33,554,432
  const size_t pm_bytes  = (size_t)NCHUNKS * NROWS * 4;   //   1,048,576
  const size_t tl_bytes  = (size_t)NROWS * 4;

  size_t off = 0;
  unsigned short* wb = (unsigned short*)(ws + off); off += wb_bytes;
  unsigned short* xb = (unsigned short*)(ws + off); off += xb_bytes;
  float* pm     = (float*)(ws + off); off += pm_bytes;
  float* psum   = (float*)(ws + off); off += pm_bytes;
  float* tlog   = (float*)(ws + off); off += tl_bytes;
  float* nll    = (float*)(ws + off); off += tl_bytes;

  if (ws_size < off) {
    fprintf(stderr, "kernel_launch: ws too small (%zu < %zu)\n", ws_size, off);
    return;
  }

  convert_w_kernel<<<4096, 256, 0, stream>>>((const float4*)W, (ushort4*)wb);
  convert_x_kernel<<<2048, 256, 0, stream>>>((const float4*)x, (ushort4*)xb);
  gemm_ce_kernel<<<ROWBLKS * NCHUNKS, 256, 0, stream>>>(xb, wb, bias, targ,
                                                        pm, psum, tlog);
  merge_rows_kernel<<<(NROWS + 255) / 256, 256, 0, stream>>>(pm, psum, tlog,
                                                             targ, nll);
  final_reduce_kernel<<<1, 256, 0, stream>>>(nll, targ, out);
}

// Round 2
// 2058.703 us; speedup vs baseline: 1.2349x; 1.2349x over previous
//
#include <hip/hip_runtime.h>
#include <math.h>
#include <stdio.h>

#define NROWS 8192
#define KDIM 2048
#define VOCAB 50257
#define VOCAB_PAD 50304   // 393 * 128
#define NTILES 393
#define NCHUNKS 32
#define BM 128
#define BN 128
#define BK 64
#define KSTEPS (KDIM / BK)   // 32
#define ROWBLKS (NROWS / BM) // 64
#define L2E 1.44269504088896340736f

typedef __bf16 bf16x8 __attribute__((ext_vector_type(8)));
typedef float f32x4 __attribute__((ext_vector_type(4)));

__device__ __forceinline__ unsigned short f2b(float f) {
  unsigned int u = __float_as_uint(f);
  u += 0x7fffu + ((u >> 16) & 1u);   // round-to-nearest-even
  return (unsigned short)(u >> 16);
}

// async global->LDS, 16B per lane, wave-uniform LDS base + lane*16
#define GLL16(g, l)                                                         \
  __builtin_amdgcn_global_load_lds(                                         \
      (const __attribute__((address_space(1))) void*)(g),                   \
      (__attribute__((address_space(3))) void*)(l), 16, 0, 0)

// ---------------- convert kernels (f32 -> bf16) ----------------
__global__ void convert_x_kernel(const float4* __restrict__ src,
                                 ushort4* __restrict__ dst) {
  const long long total = (long long)NROWS * KDIM / 4;
  for (long long i = (long long)blockIdx.x * blockDim.x + threadIdx.x;
       i < total; i += (long long)gridDim.x * blockDim.x) {
    float4 v = src[i];
    ushort4 o;
    o.x = f2b(v.x); o.y = f2b(v.y); o.z = f2b(v.z); o.w = f2b(v.w);
    dst[i] = o;
  }
}

__global__ void convert_w_kernel(const float4* __restrict__ src,
                                 ushort4* __restrict__ dst) {
  const long long total  = (long long)VOCAB_PAD * KDIM / 4;
  const long long stotal = (long long)VOCAB * KDIM / 4;
  for (long long i = (long long)blockIdx.x * blockDim.x + threadIdx.x;
       i < total; i += (long long)gridDim.x * blockDim.x) {
    float4 v;
    if (i < stotal) v = src[i];
    else { v.x = v.y = v.z = v.w = 0.f; }  // zero pad rows
    ushort4 o;
    o.x = f2b(v.x); o.y = f2b(v.y); o.z = f2b(v.z); o.w = f2b(v.w);
    dst[i] = o;
  }
}

// ---------------- fused GEMM + online softmax partials ----------------
// grid: 2048 blocks = 64 row-blocks x 32 vocab-chunks, 256 threads (4 waves, 2x2)
// LDS tiles are XOR-swizzled (T2): physical 16B-chunk = logical-chunk ^ (row&7).
// global_load_lds writes linearly, so the SOURCE address carries the inverse
// permutation (rule #21) and the ds_read applies the same XOR.
__global__ void __launch_bounds__(256, 2)
gemm_ce_kernel(const unsigned short* __restrict__ xb,
               const unsigned short* __restrict__ wb,
               const float* __restrict__ bias,
               const int* __restrict__ targ,
               float* __restrict__ pm, float* __restrict__ ps,
               float* __restrict__ tlogit) {
  __shared__ __align__(16) unsigned short Asm[BM][BK];  // 16 KB
  __shared__ __align__(16) unsigned short Bsm[BN][BK];  // 16 KB
  __shared__ float m_w[2][BM], s_w[2][BM];
  __shared__ float M_run[BM], S_run[BM];
  __shared__ int targ_s[BM];

  const int tid  = threadIdx.x;
  const int lane = tid & 63;
  const int w    = tid >> 6;       // wave 0..3
  const int wm   = w >> 1;         // wave row  (0,1) -> rows wm*64..
  const int wn   = w & 1;          // wave col  (0,1) -> cols wn*64..
  const int g    = lane >> 4;      // k-group / row-group
  const int c0   = lane & 15;
  const int swz  = c0 & 7;         // read-side row-XOR key

  const int bid    = blockIdx.x;
  const int rowblk = bid & 63;
  const int chunk  = bid >> 6;
  const int row0   = rowblk * BM;
  const int tile_start = (chunk * NTILES) / NCHUNKS;
  const int tile_end   = ((chunk + 1) * NTILES) / NCHUNKS;

  if (tid < BM) {
    int t = targ[row0 + tid];
    targ_s[tid] = (t < 0) ? 0 : t;
    M_run[tid] = -1e30f;
    S_run[tid] = 0.f;
  }
  __syncthreads();

  for (int tile = tile_start; tile < tile_end; ++tile) {
    const int vcol0 = tile * BN;

    f32x4 acc[4][4];
#pragma unroll
    for (int mf = 0; mf < 4; ++mf)
#pragma unroll
      for (int nf = 0; nf < 4; ++nf)
        acc[mf][nf] = (f32x4){0.f, 0.f, 0.f, 0.f};

    for (int kt = 0; kt < KSTEPS; ++kt) {
      const int kbase = kt * BK;
      // ---- stage A and B tiles: 16KB each, 16B/lane, 4 insts/wave/operand
#pragma unroll
      for (int it = 0; it < 4; ++it) {
        const int cbase = (it * 4 + w) * 64;       // wave-uniform chunk base
        const int cidx  = cbase + lane;            // 16B chunk index 0..1023
        const int r  = cidx >> 3;                  // tile row
        const int k8 = (cidx & 7) ^ (r & 7);       // inverse-swizzled source chunk
        const unsigned short* gA =
            xb + (size_t)(row0 + r) * KDIM + kbase + k8 * 8;
        GLL16(const_cast<unsigned short*>(gA),
              (char*)&Asm[0][0] + cbase * 16);
        const unsigned short* gB =
            wb + (size_t)(vcol0 + r) * KDIM + kbase + k8 * 8;
        GLL16(const_cast<unsigned short*>(gB),
              (char*)&Bsm[0][0] + cbase * 16);
      }
      __syncthreads();   // drains global_load_lds (vmcnt0) + LDS visible

      // ---- compute: 2 k-substeps of 32, 16 MFMA each
#pragma unroll
      for (int ks = 0; ks < 2; ++ks) {
        bf16x8 af[4], bfr[4];
#pragma unroll
        for (int mf = 0; mf < 4; ++mf)
          af[mf] = *(const bf16x8*)&Asm[wm * 64 + mf * 16 + c0]
                                      [((ks * 4 + g) ^ swz) * 8];
#pragma unroll
        for (int nf = 0; nf < 4; ++nf)
          bfr[nf] = *(const bf16x8*)&Bsm[wn * 64 + nf * 16 + c0]
                                        [((ks * 4 + g) ^ swz) * 8];
#pragma unroll
        for (int mf = 0; mf < 4; ++mf)
#pragma unroll
          for (int nf = 0; nf < 4; ++nf)
            acc[mf][nf] = __builtin_amdgcn_mfma_f32_16x16x32_bf16(
                af[mf], bfr[nf], acc[mf][nf], 0, 0, 0);
      }
      __syncthreads();   // compute done before next stage overwrites
    }

    // ---- epilogue: bias add, mask, per-row max/sumexp, target capture
    float bv[4];
    int colv[4];
#pragma unroll
    for (int nf = 0; nf < 4; ++nf) {
      const int col = vcol0 + wn * 64 + nf * 16 + c0;
      colv[nf] = col;
      bv[nf] = (col < VOCAB) ? bias[col] : 0.f;
    }
#pragma unroll
    for (int mf = 0; mf < 4; ++mf) {
#pragma unroll
      for (int reg = 0; reg < 4; ++reg) {
        const int rl = wm * 64 + mf * 16 + g * 4 + reg;  // local row
        const int t  = targ_s[rl];
        float vals[4];
        float vmax = -1e30f;
#pragma unroll
        for (int nf = 0; nf < 4; ++nf) {
          float v = acc[mf][nf][reg] + bv[nf];
          v = (colv[nf] < VOCAB) ? v : -1e30f;
          vals[nf] = v;
          vmax = fmaxf(vmax, v);
          if (colv[nf] == t) tlogit[row0 + rl] = v;  // exactly one lane matches
        }
        // reduce across the 16 lanes (c0) holding this row
        vmax = fmaxf(vmax, __shfl_xor(vmax, 1));
        vmax = fmaxf(vmax, __shfl_xor(vmax, 2));
        vmax = fmaxf(vmax, __shfl_xor(vmax, 4));
        vmax = fmaxf(vmax, __shfl_xor(vmax, 8));
        float ss = 0.f;
#pragma unroll
        for (int nf = 0; nf < 4; ++nf)
          ss += exp2f((vals[nf] - vmax) * L2E);
        ss += __shfl_xor(ss, 1);
        ss += __shfl_xor(ss, 2);
        ss += __shfl_xor(ss, 4);
        ss += __shfl_xor(ss, 8);
        if (c0 == 0) { m_w[wn][rl] = vmax; s_w[wn][rl] = ss; }
      }
    }
    __syncthreads();
    if (tid < BM) {   // combine the two col-waves, then online-merge
      const float m0 = m_w[0][tid], m1 = m_w[1][tid];
      const float s0 = s_w[0][tid], s1 = s_w[1][tid];
      const float mt = fmaxf(m0, m1);
      const float st = s0 * exp2f((m0 - mt) * L2E) + s1 * exp2f((m1 - mt) * L2E);
      const float M = M_run[tid], S = S_run[tid];
      const float nm = fmaxf(M, mt);
      S_run[tid] = S * exp2f((M - nm) * L2E) + st * exp2f((mt - nm) * L2E);
      M_run[tid] = nm;
    }
    __syncthreads();
  }

  if (tid < BM) {
    pm[(size_t)chunk * NROWS + row0 + tid] = M_run[tid];
    ps[(size_t)chunk * NROWS + row0 + tid] = S_run[tid];
  }
}

// ---------------- merge partials -> per-row NLL ----------------
__global__ void merge_rows_kernel(const float* __restrict__ pm,
                                  const float* __restrict__ ps,
                                  const float* __restrict__ tlogit,
                                  const int* __restrict__ targ,
                                  float* __restrict__ nll) {
  const int r = blockIdx.x * blockDim.x + threadIdx.x;
  if (r >= NROWS) return;
  float M = -1e30f;
#pragma unroll 4
  for (int j = 0; j < NCHUNKS; ++j) M = fmaxf(M, pm[j * NROWS + r]);
  float S = 0.f;
#pragma unroll 4
  for (int j = 0; j < NCHUNKS; ++j)
    S += ps[j * NROWS + r] * exp2f((pm[j * NROWS + r] - M) * L2E);
  const int t = targ[r];
  nll[r] = (t == -100) ? 0.f : (M + logf(S) - tlogit[r]);
}

// ---------------- final mean ----------------
__global__ void final_reduce_kernel(const float* __restrict__ nll,
                                    const int* __restrict__ targ,
                                    float* __restrict__ out) {
  __shared__ float ssum[256];
  __shared__ float scnt[256];
  const int tid = threadIdx.x;
  float s = 0.f, c = 0.f;
  for (int r = tid; r < NROWS; r += 256) {
    s += nll[r];
    c += (targ[r] != -100) ? 1.f : 0.f;
  }
  ssum[tid] = s; scnt[tid] = c;
  __syncthreads();
  for (int off = 128; off > 0; off >>= 1) {
    if (tid < off) { ssum[tid] += ssum[tid + off]; scnt[tid] += scnt[tid + off]; }
    __syncthreads();
  }
  if (tid == 0) out[0] = ssum[0] / fmaxf(scnt[0], 1.f);
}

extern "C" void kernel_launch(void* const* d_in, const int* in_sizes, int n_in,
                              void* d_out, int out_size, void* d_ws, size_t ws_size,
                              hipStream_t stream) {
  const float* x    = (const float*)d_in[0];
  const float* W    = (const float*)d_in[1];
  const float* bias = (const float*)d_in[2];
  const int*   targ = (const int*)d_in[3];
  float* out = (float*)d_out;

  char* ws = (char*)d_ws;
  const size_t wb_bytes  = (size_t)VOCAB_PAD * KDIM * 2;  // 206,045,184
  const size_t xb_bytes  = (size_t)NROWS * KDIM * 2;      //  33,554,432
  const size_t pm_bytes  = (size_t)NCHUNKS * NROWS * 4;   //   1,048,576
  const size_t tl_bytes  = (size_t)NROWS * 4;

  size_t off = 0;
  unsigned short* wb = (unsigned short*)(ws + off); off += wb_bytes;
  unsigned short* xb = (unsigned short*)(ws + off); off += xb_bytes;
  float* pm     = (float*)(ws + off); off += pm_bytes;
  float* psum   = (float*)(ws + off); off += pm_bytes;
  float* tlog   = (float*)(ws + off); off += tl_bytes;
  float* nll    = (float*)(ws + off); off += tl_bytes;

  if (ws_size < off) {
    fprintf(stderr, "kernel_launch: ws too small (%zu < %zu)\n", ws_size, off);
    return;
  }

  convert_w_kernel<<<4096, 256, 0, stream>>>((const float4*)W, (ushort4*)wb);
  convert_x_kernel<<<2048, 256, 0, stream>>>((const float4*)x, (ushort4*)xb);
  gemm_ce_kernel<<<ROWBLKS * NCHUNKS, 256, 0, stream>>>(xb, wb, bias, targ,
                                                        pm, psum, tlog);
  merge_rows_kernel<<<(NROWS + 255) / 256, 256, 0, stream>>>(pm, psum, tlog,
                                                             targ, nll);
  final_reduce_kernel<<<1, 256, 0, stream>>>(nll, targ, out);
}